// Round 16
// baseline (145.018 us; speedup 1.0000x reference)
//
#include <hip/hip_runtime.h>
#include <math.h>

#define NLAB 2000
#define BATCH 1024
#define LAMBDA_SMOOTH 0.1f

#define RPG 16           // batch rows per group
#define NRG 64           // row groups (1024/16)
#define ES 8             // edge slices (= slices per image)
#define NB 512           // grid = 64 rg x 8 es; 2 blocks/CU -> whole grid resident
#define IMG_U16 32496    // 2000*16 + 62 pad-granules * 8 u16 = 64992 B
#define IMG_V4  4062     // same in uint4
#define TAG_MAGIC 0xC0FFEE5111111111ull
#define OUT_MAGIC 0x5A5AC3D2u
#define SPIN_MAX  65536

typedef _Float16 h2 __attribute__((ext_vector_type(2)));

// u16 slot of (label l, row 0): 16 u16 per label + one 16B pad granule per 32 labels
__device__ __forceinline__ int slot16(int l) { return (l << 4) + ((l >> 5) << 3); }

// one packed sub + one v_dot2_f32_f16: accumulates (a-b).(a-b) for 2 rows
__device__ __forceinline__ float dot_acc(unsigned ua, unsigned ub, float acc) {
    const h2 a = __builtin_bit_cast(h2, ua);
    const h2 b = __builtin_bit_cast(h2, ub);
    const h2 d = a - b;
    return __builtin_amdgcn_fdot2(d, d, acc, false);
}

// convert rows r0..r0+3 of label l -> packed u64 of 4 f16
__device__ __forceinline__ unsigned long long conv4(
        const float* __restrict__ logits, const float* __restrict__ labels,
        int r0, int l) {
    float y[4];
#pragma unroll
    for (int q = 0; q < 4; ++q) {
        const int idx = (r0 + q) * NLAB + l;        // coalesced across lanes
        const float lg  = logits[idx];
        const float lab = labels[idx];
        const float sg  = 1.0f / (1.0f + __expf(-lg));
        const bool ann  = (lab == 0.0f) || (lab == 1.0f);
        y[q] = ann ? (2.0f * lab - 1.0f) : (2.0f * sg - 1.0f);
    }
    h2 h0; h0.x = (_Float16)y[0]; h0.y = (_Float16)y[1];
    h2 h1; h1.x = (_Float16)y[2]; h1.y = (_Float16)y[3];
    return (unsigned long long)__builtin_bit_cast(unsigned, h0)
         | ((unsigned long long)__builtin_bit_cast(unsigned, h1) << 32);
}

// ---------------------------------------------------------------------------
// Single fused kernel. Block (rg, es): converts slice es of image rg
// (250 labels x 16 rows, no duplication), publishes it via relaxed agent
// u64 atomic data stores + RELEASE tag (distinct address per slice), then
// consumes the 7 sibling slices (L2-inv BEFORE spin so post-tag reads are
// never stale), runs its edge slice, and finalizes via the R14 tag trick.
// Deadlock-proof: produce-before-wait + full-grid residency + bounded-spin
// fallback (locally re-convert a missing slice; bitwise-identical values).
// ---------------------------------------------------------------------------
__global__ __launch_bounds__(1024, 8) void fused_kernel(
        const float* __restrict__ logits, const float* __restrict__ labels,
        const float* __restrict__ ew, const int* __restrict__ li,
        const int* __restrict__ ri, int nEdges,
        unsigned long long* __restrict__ yPack64,
        unsigned long long* __restrict__ tags,
        unsigned long long* __restrict__ slots,
        float scale, float* __restrict__ out) {
    __shared__ uint4 shv[IMG_V4];               // 64992 B
    __shared__ float red[16];
    __shared__ int   missing[8];
    const int x   = blockIdx.x & 7;             // XCD slot
    const int j   = blockIdx.x >> 3;
    const int rg  = x * 8 + (j & 7);
    const int es  = j >> 3;
    const int tid = threadIdx.x;
    ushort* shu = (ushort*)shv;

    // ---- Phase 1: convert own slice into LDS + global (atomic u64 stores) ----
    const int part = tid >> 8;                  // 0..3 -> rows part*4..part*4+3
    const int lidx = tid & 255;                 // 0..255 (active < 250)
    if (lidx < 250) {
        const int l  = es * 250 + lidx;
        const int r0 = rg * RPG + part * 4;
        const unsigned long long v = conv4(logits, labels, r0, l);
        const int u16o = slot16(l) + part * 4;  // %4 == 0 -> u64-aligned
        *(unsigned long long*)(shu + u16o) = v;
        __hip_atomic_store(&yPack64[((size_t)rg * IMG_U16 + u16o) >> 2], v,
                           __ATOMIC_RELAXED, __HIP_MEMORY_SCOPE_AGENT);
    }
    __syncthreads();                            // drains vmcnt -> data visible
    if (tid == 0)
        __hip_atomic_store(&tags[rg * 8 + es], TAG_MAGIC,
                           __ATOMIC_RELEASE, __HIP_MEMORY_SCOPE_AGENT);
    __threadfence();   // L2-inv BEFORE spin: post-tag reads can't be stale

    // ---- Phase 2: wait for sibling slices (bounded spin + fallback) ----
    if (tid < 8) {
        int m = 0;
        if (tid != es) {
            int spins = 0;
            while (__hip_atomic_load(&tags[rg * 8 + tid], __ATOMIC_RELAXED,
                                     __HIP_MEMORY_SCOPE_AGENT) != TAG_MAGIC) {
                if (++spins > SPIN_MAX) { m = 1; break; }
                __builtin_amdgcn_s_sleep(1);
            }
        }
        missing[tid] = m;
    }
    __syncthreads();
    // fallback: deterministically re-convert missing slices into LDS only
#pragma unroll 1
    for (int ms = 0; ms < 8; ++ms) {
        if (missing[ms] && lidx < 250) {
            const int l = ms * 250 + lidx;
            const unsigned long long v = conv4(logits, labels, rg * RPG + part * 4, l);
            *(unsigned long long*)(shu + slot16(l) + part * 4) = v;
        }
    }
    // stage remaining slices from global (L2-shared across same-rg blocks)
    {
        const unsigned long long* src = yPack64 + (((size_t)rg * IMG_U16) >> 2);
        for (int i = tid; i < IMG_V4; i += 1024) {
            int s = 0;
            s += (i >= 507) + (i >= 1015) + (i >= 1523) + (i >= 2031)
               + (i >= 2539) + (i >= 3046) + (i >= 3554);
            if (s == es || missing[s]) continue;
            unsigned long long* dst = (unsigned long long*)&shv[i];
            dst[0] = src[(size_t)(i << 1)];
            dst[1] = src[(size_t)(i << 1) + 1];
        }
    }
    __syncthreads();
    const ushort* sh = (const ushort*)shv;

    // ---- Phase 3: edge slice reduction (R12/R15 loop) ----
    const int per   = (nEdges + ES - 1) / ES;
    const int e0    = es * per;
    const int e1    = min(e0 + per, nEdges);
    const int niter = (per + 2047) >> 11;       // 2 edges/thread/iter

    float acc = 0.0f;
    for (int k = 0; k < niter; ++k) {
        const int ea = e0 + tid + (k << 11);
        const int eb = ea + 1024;
        int eca = min(ea, e1 - 1); if (eca < e0) eca = e0;
        int ecb = min(eb, e1 - 1); if (ecb < e0) ecb = e0;

        const int   la = li[eca], ra = ri[eca];
        const int   lb = li[ecb], rb = ri[ecb];
        const float wa = (ea < e1) ? ew[eca] : 0.0f;
        const float wb = (eb < e1) ? ew[ecb] : 0.0f;

        const int sla = slot16(la), sra = slot16(ra);
        const int slb = slot16(lb), srb = slot16(rb);
        const uint4 Aa0 = *(const uint4*)(sh + sla);
        const uint4 Aa1 = *(const uint4*)(sh + sla + 8);
        const uint4 Ba0 = *(const uint4*)(sh + sra);
        const uint4 Ba1 = *(const uint4*)(sh + sra + 8);
        const uint4 Ab0 = *(const uint4*)(sh + slb);
        const uint4 Ab1 = *(const uint4*)(sh + slb + 8);
        const uint4 Bb0 = *(const uint4*)(sh + srb);
        const uint4 Bb1 = *(const uint4*)(sh + srb + 8);

        float sa = 0.0f;
        sa = dot_acc(Aa0.x, Ba0.x, sa);
        sa = dot_acc(Aa0.y, Ba0.y, sa);
        sa = dot_acc(Aa0.z, Ba0.z, sa);
        sa = dot_acc(Aa0.w, Ba0.w, sa);
        sa = dot_acc(Aa1.x, Ba1.x, sa);
        sa = dot_acc(Aa1.y, Ba1.y, sa);
        sa = dot_acc(Aa1.z, Ba1.z, sa);
        sa = dot_acc(Aa1.w, Ba1.w, sa);
        float sb = 0.0f;
        sb = dot_acc(Ab0.x, Bb0.x, sb);
        sb = dot_acc(Ab0.y, Bb0.y, sb);
        sb = dot_acc(Ab0.z, Bb0.z, sb);
        sb = dot_acc(Ab0.w, Bb0.w, sb);
        sb = dot_acc(Ab1.x, Bb1.x, sb);
        sb = dot_acc(Ab1.y, Bb1.y, sb);
        sb = dot_acc(Ab1.z, Bb1.z, sb);
        sb = dot_acc(Ab1.w, Bb1.w, sb);

        acc = fmaf(wa, sa, acc);
        acc = fmaf(wb, sb, acc);
    }

#pragma unroll
    for (int off = 32; off > 0; off >>= 1)
        acc += __shfl_down(acc, off, 64);
    if ((tid & 63) == 0) red[tid >> 6] = acc;
    __syncthreads();
    if (tid == 0) {
        float t = 0.0f;
#pragma unroll
        for (int i = 0; i < 16; ++i) t += red[i];
        const unsigned long long pack =
            ((unsigned long long)OUT_MAGIC << 32) | (unsigned long long)__float_as_uint(t);
        __hip_atomic_store(&slots[blockIdx.x], pack,
                           __ATOMIC_RELAXED, __HIP_MEMORY_SCOPE_AGENT);
    }

    // ---- Phase 4: finalize (block 0, wave 0) ----
    if (blockIdx.x == 0 && tid < 64) {
        float s = 0.0f;
        for (int i = tid; i < NB; i += 64) {    // 8 slots per lane, fixed order
            unsigned long long v;
            for (;;) {
                v = __hip_atomic_load(&slots[i], __ATOMIC_RELAXED,
                                      __HIP_MEMORY_SCOPE_AGENT);
                if ((unsigned)(v >> 32) == OUT_MAGIC) break;
                __builtin_amdgcn_s_sleep(2);
            }
            s += __uint_as_float((unsigned)v);
        }
#pragma unroll
        for (int off = 32; off > 0; off >>= 1)
            s += __shfl_down(s, off, 64);
        if (tid == 0) out[0] = scale * s;
    }
}

// ---------------------------------------------------------------------------
extern "C" void kernel_launch(void* const* d_in, const int* in_sizes, int n_in,
                              void* d_out, int out_size, void* d_ws, size_t ws_size,
                              hipStream_t stream) {
    const float* logits = (const float*)d_in[0];
    const float* labels = (const float*)d_in[1];
    const float* ew     = (const float*)d_in[2];
    const int*   li     = (const int*)d_in[3];
    const int*   ri     = (const int*)d_in[4];
    float* out          = (float*)d_out;

    const int nEdges = in_sizes[2];

    // ws layout: yPack (64*64992 B = 4159488), slots[512], tags[512]
    unsigned long long* yPack64 = (unsigned long long*)d_ws;
    unsigned long long* slots   = (unsigned long long*)((char*)d_ws + 4159488);
    unsigned long long* tags    = slots + NB;

    const float scale = LAMBDA_SMOOTH / ((float)BATCH * (float)nEdges);
    fused_kernel<<<NB, 1024, 0, stream>>>(logits, labels, ew, li, ri, nEdges,
                                          yPack64, tags, slots, scale, out);
}

// Round 17
// 17.094 us; speedup vs baseline: 8.4834x; 8.4834x over previous
//
#include <hip/hip_runtime.h>
#include <math.h>

#define NLAB 2000
#define BATCH 1024
#define LAMBDA_SMOOTH 0.1f

#define RPG 16           // batch rows per group
#define NRG 64           // row groups (1024/16)
#define ES 8             // edge slices in K2
#define NB2 512          // K2 grid = 64 rg x 8 es  (2 blocks/CU, 100% occ)
#define IMG_U16 32496    // 2000*16 + 62 pad-granules * 8 u16 = 64992 B
#define IMG_V4  4062     // same in uint4 (64992/16)
#define MAGIC 0x5A5AC3D2u

typedef _Float16 h2 __attribute__((ext_vector_type(2)));

// u16 slot of (label l, row 0): 16 u16 per label + one 16B pad granule per
// 32 labels -> gather start positions cover 8 distinct bank-quads.
__device__ __forceinline__ int slot16(int l) { return (l << 4) + ((l >> 5) << 3); }

// one packed sub + one v_dot2_f32_f16: accumulates (a-b).(a-b) for 2 rows
__device__ __forceinline__ float dot_acc(unsigned ua, unsigned ub, float acc) {
    const h2 a = __builtin_bit_cast(h2, ua);
    const h2 b = __builtin_bit_cast(h2, ub);
    const h2 d = a - b;
    return __builtin_amdgcn_fdot2(d, d, acc, false);
}

// ---------------------------------------------------------------------------
// K1: convert + pack (f16). grid 1024 = 64 rg x 8 slices x 2 halves.
// Each block: 8 rows x 250 labels, 16 loads/thread, ONE uint4 write.
// XCD-matched: x = bid&7 is the XCD that also consumes image rg in K2.
// ---------------------------------------------------------------------------
__global__ __launch_bounds__(256) void convert_pack_kernel(
        const float* __restrict__ logits, const float* __restrict__ labels,
        ushort* __restrict__ yPack) {
    const int x    = blockIdx.x & 7;
    const int rg   = (x << 3) | ((blockIdx.x >> 3) & 7);
    const int s    = (blockIdx.x >> 6) & 7;
    const int half = blockIdx.x >> 9;
    const int t    = threadIdx.x;
    if (t >= 250) return;
    const int l  = s * 250 + t;
    const int r0 = rg * RPG + half * 8;

    unsigned p[4];
#pragma unroll
    for (int h = 0; h < 4; ++h) {
        float y2[2];
#pragma unroll
        for (int q = 0; q < 2; ++q) {
            const int idx = (r0 + 2 * h + q) * NLAB + l;   // coalesced in t
            const float lg  = logits[idx];
            const float lab = labels[idx];
            const float sg  = 1.0f / (1.0f + __expf(-lg));
            const bool ann  = (lab == 0.0f) || (lab == 1.0f);
            y2[q] = ann ? (2.0f * lab - 1.0f) : (2.0f * sg - 1.0f);
        }
        h2 hv;
        hv.x = (_Float16)y2[0];
        hv.y = (_Float16)y2[1];
        p[h] = __builtin_bit_cast(unsigned, hv);
    }
    uint4 v; v.x = p[0]; v.y = p[1]; v.z = p[2]; v.w = p[3];
    *(uint4*)(yPack + (size_t)rg * IMG_U16 + slot16(l) + half * 8) = v;
}

// ---------------------------------------------------------------------------
// K2: edge reduction + fused finalize.
// Relaxed agent-scope u64 atomic tag carries the partial -> no fence/counter.
// ---------------------------------------------------------------------------
__global__ __launch_bounds__(1024, 8) void edge_reduce_kernel(
        const ushort* __restrict__ yPack, const float* __restrict__ ew,
        const int* __restrict__ li, const int* __restrict__ ri,
        int nEdges, unsigned long long* __restrict__ slots,
        float scale, float* __restrict__ out) {
    __shared__ uint4 shv[IMG_V4];               // 64992 B
    __shared__ float red[16];
    const int x   = blockIdx.x & 7;             // XCD slot
    const int j   = blockIdx.x >> 3;
    const int rg  = x * 8 + (j & 7);
    const int es  = j >> 3;
    const int tid = threadIdx.x;

    const uint4* src = (const uint4*)(yPack + (size_t)rg * IMG_U16);
    for (int i = tid; i < IMG_V4; i += 1024) shv[i] = src[i];
    __syncthreads();
    const ushort* sh = (const ushort*)shv;

    const int per   = (nEdges + ES - 1) / ES;
    const int e0    = es * per;
    const int e1    = min(e0 + per, nEdges);
    const int niter = (per + 2047) >> 11;       // 2 edges/thread/iter, uniform

    float acc = 0.0f;
    for (int k = 0; k < niter; ++k) {
        const int ea = e0 + tid + (k << 11);
        const int eb = ea + 1024;
        int eca = min(ea, e1 - 1); if (eca < e0) eca = e0;
        int ecb = min(eb, e1 - 1); if (ecb < e0) ecb = e0;

        const int   la = li[eca], ra = ri[eca];
        const int   lb = li[ecb], rb = ri[ecb];
        const float wa = (ea < e1) ? ew[eca] : 0.0f;
        const float wb = (eb < e1) ? ew[ecb] : 0.0f;

        const int sla = slot16(la), sra = slot16(ra);
        const int slb = slot16(lb), srb = slot16(rb);
        const uint4 Aa0 = *(const uint4*)(sh + sla);
        const uint4 Aa1 = *(const uint4*)(sh + sla + 8);
        const uint4 Ba0 = *(const uint4*)(sh + sra);
        const uint4 Ba1 = *(const uint4*)(sh + sra + 8);
        const uint4 Ab0 = *(const uint4*)(sh + slb);
        const uint4 Ab1 = *(const uint4*)(sh + slb + 8);
        const uint4 Bb0 = *(const uint4*)(sh + srb);
        const uint4 Bb1 = *(const uint4*)(sh + srb + 8);

        float sa = 0.0f;
        sa = dot_acc(Aa0.x, Ba0.x, sa);
        sa = dot_acc(Aa0.y, Ba0.y, sa);
        sa = dot_acc(Aa0.z, Ba0.z, sa);
        sa = dot_acc(Aa0.w, Ba0.w, sa);
        sa = dot_acc(Aa1.x, Ba1.x, sa);
        sa = dot_acc(Aa1.y, Ba1.y, sa);
        sa = dot_acc(Aa1.z, Ba1.z, sa);
        sa = dot_acc(Aa1.w, Ba1.w, sa);
        float sb = 0.0f;
        sb = dot_acc(Ab0.x, Bb0.x, sb);
        sb = dot_acc(Ab0.y, Bb0.y, sb);
        sb = dot_acc(Ab0.z, Bb0.z, sb);
        sb = dot_acc(Ab0.w, Bb0.w, sb);
        sb = dot_acc(Ab1.x, Bb1.x, sb);
        sb = dot_acc(Ab1.y, Bb1.y, sb);
        sb = dot_acc(Ab1.z, Bb1.z, sb);
        sb = dot_acc(Ab1.w, Bb1.w, sb);

        acc = fmaf(wa, sa, acc);
        acc = fmaf(wb, sb, acc);
    }

#pragma unroll
    for (int off = 32; off > 0; off >>= 1)
        acc += __shfl_down(acc, off, 64);
    if ((tid & 63) == 0) red[tid >> 6] = acc;
    __syncthreads();
    if (tid == 0) {
        float t = 0.0f;
#pragma unroll
        for (int i = 0; i < 16; ++i) t += red[i];
        const unsigned long long pack =
            ((unsigned long long)MAGIC << 32) | (unsigned long long)__float_as_uint(t);
        __hip_atomic_store(&slots[blockIdx.x], pack,
                           __ATOMIC_RELAXED, __HIP_MEMORY_SCOPE_AGENT);
    }

    // ---- finalize: block 0, wave 0 only ----
    if (blockIdx.x == 0 && tid < 64) {
        float s = 0.0f;
        for (int i = tid; i < NB2; i += 64) {   // 8 slots per lane, fixed order
            unsigned long long v;
            for (;;) {
                v = __hip_atomic_load(&slots[i], __ATOMIC_RELAXED,
                                      __HIP_MEMORY_SCOPE_AGENT);
                if ((unsigned)(v >> 32) == MAGIC) break;
                __builtin_amdgcn_s_sleep(2);
            }
            s += __uint_as_float((unsigned)v);
        }
#pragma unroll
        for (int off = 32; off > 0; off >>= 1)
            s += __shfl_down(s, off, 64);
        if (tid == 0) out[0] = scale * s;
    }
}

// ---------------------------------------------------------------------------
extern "C" void kernel_launch(void* const* d_in, const int* in_sizes, int n_in,
                              void* d_out, int out_size, void* d_ws, size_t ws_size,
                              hipStream_t stream) {
    const float* logits = (const float*)d_in[0];
    const float* labels = (const float*)d_in[1];
    const float* ew     = (const float*)d_in[2];
    const int*   li     = (const int*)d_in[3];
    const int*   ri     = (const int*)d_in[4];
    float* out          = (float*)d_out;

    const int nEdges = in_sizes[2];

    // workspace: yPack images (64 * 64992 B = 4.16 MB, 8B-aligned), slots
    ushort* yPack = (ushort*)d_ws;
    unsigned long long* slots =
        (unsigned long long*)((char*)d_ws + (size_t)NRG * IMG_U16 * sizeof(ushort));

    convert_pack_kernel<<<NRG * 8 * 2, 256, 0, stream>>>(logits, labels, yPack);

    const float scale = LAMBDA_SMOOTH / ((float)BATCH * (float)nEdges);
    edge_reduce_kernel<<<NB2, 1024, 0, stream>>>(yPack, ew, li, ri, nEdges,
                                                 slots, scale, out);
}